// Round 3
// baseline (313.413 us; speedup 1.0000x reference)
//
#include <hip/hip_runtime.h>

#define B_    8
#define C_    64
#define H_    128
#define W_    128
#define K_    9
#define J_    18     // 2*K
#define COUT_ 64
#define TPX   16     // pixels per tile
#define TILES 4      // tiles per block (half a row)
#define CK    576    // C_*K_
#define SROW  584    // sbuf row stride (bf16 elems)
#define NW81  (C_ * 81)                 // 5184 packed weight words
#define L2E   1.4426950408889634f       // log2(e), folded into conv weights+bias

typedef __attribute__((ext_vector_type(8))) short short8;
typedef __attribute__((ext_vector_type(4))) float float4v;
typedef __attribute__((ext_vector_type(2))) float f32x2;

// round-to-nearest-even fp32 -> bf16
__device__ __forceinline__ unsigned short f2bf(float f) {
    unsigned int u = __float_as_uint(f);
    u = u + 0x7fffu + ((u >> 16) & 1u);
    return (unsigned short)(u >> 16);
}

// conv tap (r*3+s) -> strip index r*7+s. constexpr everywhere (earlier:
// runtime-indexed S[] -> scratch demotion -> GB-scale spill).
constexpr int TMAP[9] = {0, 1, 2, 7, 8, 9, 14, 15, 16};

// -------- pre-kernel: NCHW -> NHWC transpose of x into workspace --------
__global__ __launch_bounds__(256)
void nchw_to_nhwc(const float* __restrict__ x, float* __restrict__ xt) {
    __shared__ float tile[64][65];
    const int bid = blockIdx.x;          // b*256 + h*2 + wt
    const int wt  = bid & 1;
    const int h   = (bid >> 1) & 127;
    const int b   = bid >> 8;
    const int w0  = wt << 6;
    const int q   = threadIdx.x >> 6;
    const int l   = threadIdx.x & 63;
    #pragma unroll
    for (int r = 0; r < 16; r++) {
        const int c = q * 16 + r;
        tile[c][l] = x[((size_t)(b * C_ + c) * H_ + h) * W_ + w0 + l];
    }
    __syncthreads();
    #pragma unroll
    for (int r = 0; r < 16; r++) {
        const int w = q * 16 + r;
        xt[((size_t)(b * H_ + h) * W_ + w0 + w) * C_ + l] = tile[l][w];
    }
}

// -------- pre-kernel: dw f32->bf16 AND offset-weight pair-pack ----------
__global__ __launch_bounds__(256)
void prep_weights(const float* __restrict__ dw, unsigned short* __restrict__ dwb,
                  const float* __restrict__ ow, unsigned int* __restrict__ owp) {
    const int bid = blockIdx.x;
    const int dwblocks = (CK * COUT_) / 256;   // 144, exact
    if (bid < dwblocks) {
        const int i = bid * 256 + threadIdx.x;
        dwb[i] = f2bf(dw[i]);
    } else {
        const int i = (bid - dwblocks) * 256 + threadIdx.x;
        if (i < NW81) {
            const int c = i / 81, r = i - c * 81;
            const int k = r / 9,  t = r - k * 9;
            const float* s = ow + c * 162 + k * 18 + t;   // (2k)*9 = k*18
            owp[i] = (unsigned int)f2bf(s[0] * L2E) |
                     ((unsigned int)f2bf(s[9] * L2E) << 16);
        }
    }
}

// ---- conv inner loop: full unroll via template recursion (pragma-unroll
// bailed at this body size earlier -> scratch). Word T = k*9 + t holds the
// bf16 (dy,dx) weight pair of output-pair k, tap t. One v_pk_fma_f32 per
// pixel per word.
template<int T>
__device__ __forceinline__ void conv_steps(const unsigned int* __restrict__ owc,
                                           const float (&S)[28], f32x2 (&v2)[4][9]) {
    if constexpr (T < 81) {
        const unsigned int pw = owc[T];
        const f32x2 w2 = {__uint_as_float(pw << 16),
                          __uint_as_float(pw & 0xffff0000u)};
        constexpr int k = T / 9;
        constexpr int p = TMAP[T % 9];
        #pragma unroll
        for (int px = 0; px < 4; px++) {
            const float s = S[p + px];
            v2[px][k] = __builtin_elementwise_fma(w2, (f32x2){s, s}, v2[px][k]);
        }
        conv_steps<T + 1>(owc, S, v2);
    }
}

// ---- per-pixel bilinear taps ----
// (round-1 lesson): dy/dx are bilinear SAMPLE COORDINATES — the sampled
// value has a dy*dx cross term + constant term, so 1/sum does NOT commute
// through the einsum. Normalize here via v_rcp_f32 (invisible under bf16).
template<int I>
__device__ __forceinline__ void taps_px(const f32x2 (&w)[9], const float inv,
                                        const float (&S)[28],
                                        unsigned short* __restrict__ sb) {
    #pragma unroll
    for (int k = 0; k < 9; k++) {
        const float dy = w[k].x * inv;
        const float dx = w[k].y * inv;
        const int base = TMAP[k] + I;              // constexpr-folded
        const float a  = S[base],     bb = S[base + 1];
        const float c  = S[base + 7], dd = S[base + 8];
        const float top = fmaf(dx, bb - a, a);
        const float bot = fmaf(dx, dd - c, c);
        sb[k] = f2bf(fmaf(dy, bot - top, top));
    }
}

// ---- 4x7 input strip load (rows h-1..h+2, cols wbase-1..wbase+5) ----
template<bool NHWC>
__device__ __forceinline__ void load_strip(const float* __restrict__ xsrc,
                                           int b, int h, int wbase, int lane,
                                           float (&S)[28]) {
    if (h >= 1 && h <= H_ - 3 && wbase >= 1 && wbase <= W_ - 6) {
        // interior fast path: bounds are wave-uniform -> scalar branch
        const float* p0 = NHWC
            ? xsrc + ((size_t)(b * H_ + (h - 1)) * W_ + (wbase - 1)) * C_ + lane
            : xsrc + ((size_t)(b * C_ + lane) * H_ + (h - 1)) * W_ + (wbase - 1);
        const int rs = NHWC ? (W_ * C_) : W_;
        const int cs = NHWC ? C_ : 1;
        #pragma unroll
        for (int r = 0; r < 4; r++)
            #pragma unroll
            for (int s = 0; s < 7; s++)
                S[r * 7 + s] = p0[r * rs + s * cs];
    } else {
        #pragma unroll
        for (int r = 0; r < 4; r++) {
            const int y = h - 1 + r;
            const bool yv = (unsigned)y < (unsigned)H_;
            #pragma unroll
            for (int s = 0; s < 7; s++) {
                const int xx = wbase - 1 + s;
                const bool ok = yv && ((unsigned)xx < (unsigned)W_);
                const float* p = NHWC
                    ? xsrc + ((size_t)(b * H_ + (y & 127)) * W_ + (xx & 127)) * C_ + lane
                    : xsrc + ((size_t)(b * C_ + lane) * H_ + (y & 127)) * W_ + (xx & 127);
                S[r * 7 + s] = ok ? *p : 0.0f;
            }
        }
    }
}

// -------- fused kernel --------
// Round-2 lesson: latency-bound (VALUBusy 51%, Mfma 3%, HBM 5%, occ 31%).
// Fix: 4 tiles per block (stage ow_s once, hoist phase-B constants),
// register-prefetch next tile's strip under exp/reduce/taps, XCD-chunked
// block mapping (one batch image per XCD's private L2).
template<bool NHWC, bool PREB, bool PREP>
__global__ __launch_bounds__(256, 3)
void dcn_fused(const float* __restrict__ xsrc,
               const float* __restrict__ ow,
               const unsigned int* __restrict__ owp,
               const float* __restrict__ ob,
               const float* __restrict__ dw,
               const unsigned short* __restrict__ dwb,
               const float* __restrict__ db,
               float* __restrict__ out) {
    __shared__ __align__(16) unsigned int ow_s[NW81];                 // 20736 B
    __shared__ __align__(16) unsigned short sbuf[TPX * SROW];         // 18688 B -> 39424 B

    const int tid  = threadIdx.x;
    const int wave = tid >> 6;
    const int lane = tid & 63;

    // XCD-chunked bijective swizzle (2048 blocks, 8 XCDs, 256 each):
    // XCD x gets logical range [x*256,(x+1)*256) = all half-rows of image x.
    const int bid     = blockIdx.x;
    const int logical = (bid & 7) * 256 + (bid >> 3);
    const int b       = logical >> 8;
    const int h       = (logical >> 1) & 127;
    const int w0base  = (logical & 1) << 6;       // 0 or 64

    // stage packed offset weights (once per 4 tiles)
    if (PREP) {
        #pragma unroll
        for (int i = 0; i < 21; i++) {               // 5184 = 20*256 + 64
            const int idx = tid + i * 256;
            if (idx < NW81) ow_s[idx] = owp[idx];    // coalesced u32 copy
        }
    } else {
        for (int i = tid; i < NW81; i += 256) {      // fallback: pack in-kernel
            const int c = i / 81, r = i - c * 81;
            const int k = r / 9,  t = r - k * 9;
            const float* s = ow + c * 162 + k * 18 + t;
            ow_s[i] = (unsigned int)f2bf(s[0] * L2E) |
                      ((unsigned int)f2bf(s[9] * L2E) << 16);
        }
    }

    // hoisted phase-B constants (fixed across tiles)
    const int quad = lane >> 4;
    const int o    = (wave << 4) + (lane & 15);
    const unsigned short* arow  = sbuf + (lane & 15) * SROW + quad * 8;
    const unsigned short* bbase = PREB ? (dwb + (size_t)o * CK + quad * 8) : nullptr;
    const float* brow0 = PREB ? nullptr : (dw + (size_t)o * CK + quad * 8);
    const float bias = db[o];
    float* outrow = out + ((size_t)(b * COUT_ + o) * H_ + h) * W_;

    const unsigned int* owc = ow_s + lane * 81;
    const float2* obp = (const float2*)(ob + lane * J_);

    __syncthreads();

    float S[28], S2[28];
    load_strip<NHWC>(xsrc, b, h, w0base + (wave << 2), lane, S);

    #pragma unroll 1
    for (int tt = 0; tt < TILES; tt++) {
        const int w0 = w0base + (tt << 4);

        // ---- phase A: conv + softmax + bilinear, 4 px per wave ----
        f32x2 v2[4][9];
        #pragma unroll
        for (int p = 0; p < 9; p++) {
            const float2 f = obp[p];                 // bias, L1-hot (4.6 KB)
            const f32x2 b2 = {f.x * L2E, f.y * L2E};
            v2[0][p] = b2; v2[1][p] = b2; v2[2][p] = b2; v2[3][p] = b2;
        }
        conv_steps<0>(owc, S, v2);

        // prefetch next tile's strip NOW: ~1100-cycle window (exp + reduce +
        // taps) before the barrier's vmcnt-drain claims the loads.
        if (tt + 1 < TILES)
            load_strip<NHWC>(xsrc, b, h, w0base + ((tt + 1) << 4) + (wave << 2), lane, S2);

        // exp2 + per-px local sums. No max-subtraction: logits bounded
        // (|w|~0.05 scale), exp2 args ~ +-15, fp32-safe.
        float psum[4];
        #pragma unroll
        for (int px = 0; px < 4; px++) {
            float s = 0.0f;
            #pragma unroll
            for (int k = 0; k < 9; k++) {
                f32x2 e;
                e.x = __builtin_amdgcn_exp2f(v2[px][k].x);
                e.y = __builtin_amdgcn_exp2f(v2[px][k].y);
                v2[px][k] = e;
                s += e.x + e.y;
            }
            psum[px] = s;
        }

        // cross-lane softmax denominators (64 lanes x 18 = channel axis),
        // 4 px interleaved; xor<32 via single-inst ds_swizzle, xor32 via shfl.
        #pragma unroll
        for (int px = 0; px < 4; px++) psum[px] += __shfl_xor(psum[px], 32, 64);
#define RED_LEVEL(PAT) do { \
        const float r0_ = __uint_as_float((unsigned)__builtin_amdgcn_ds_swizzle((int)__float_as_uint(psum[0]), (PAT))); \
        const float r1_ = __uint_as_float((unsigned)__builtin_amdgcn_ds_swizzle((int)__float_as_uint(psum[1]), (PAT))); \
        const float r2_ = __uint_as_float((unsigned)__builtin_amdgcn_ds_swizzle((int)__float_as_uint(psum[2]), (PAT))); \
        const float r3_ = __uint_as_float((unsigned)__builtin_amdgcn_ds_swizzle((int)__float_as_uint(psum[3]), (PAT))); \
        psum[0] += r0_; psum[1] += r1_; psum[2] += r2_; psum[3] += r3_; \
    } while (0)
        RED_LEVEL(0x401F);   // xor 16
        RED_LEVEL(0x201F);   // xor 8
        RED_LEVEL(0x101F);   // xor 4
        RED_LEVEL(0x081F);   // xor 2
        RED_LEVEL(0x041F);   // xor 1
#undef RED_LEVEL

        const float inv0 = __builtin_amdgcn_rcpf(psum[0]);
        const float inv1 = __builtin_amdgcn_rcpf(psum[1]);
        const float inv2 = __builtin_amdgcn_rcpf(psum[2]);
        const float inv3 = __builtin_amdgcn_rcpf(psum[3]);

        unsigned short* sb = sbuf + (wave << 2) * SROW + lane * K_;
        taps_px<0>(v2[0], inv0, S, sb);
        taps_px<1>(v2[1], inv1, S, sb + SROW);
        taps_px<2>(v2[2], inv2, S, sb + 2 * SROW);
        taps_px<3>(v2[3], inv3, S, sb + 3 * SROW);

        __syncthreads();

        // ---- phase B: MFMA einsum. Per wave: 16 px x 16 outs, K=576 ----
        float4v acc = {0.f, 0.f, 0.f, 0.f};
        #pragma unroll
        for (int t = 0; t < 18; t++) {
            short8 afrag = *(const short8*)(arow + t * 32);
            short8 bfrag;
            if (PREB) {
                bfrag = *(const short8*)(bbase + t * 32);
            } else {
                const float* brow = brow0 + t * 32;
                float4 b0 = *(const float4*)brow;
                float4 b1 = *(const float4*)(brow + 4);
                union { short8 s8; unsigned short u[8]; } bfu;
                bfu.u[0] = f2bf(b0.x); bfu.u[1] = f2bf(b0.y); bfu.u[2] = f2bf(b0.z); bfu.u[3] = f2bf(b0.w);
                bfu.u[4] = f2bf(b1.x); bfu.u[5] = f2bf(b1.y); bfu.u[6] = f2bf(b1.z); bfu.u[7] = f2bf(b1.w);
                bfrag = bfu.s8;
            }
            acc = __builtin_amdgcn_mfma_f32_16x16x32_bf16(afrag, bfrag, acc, 0, 0, 0);
        }
        float4 res;
        res.x = acc[0] + bias; res.y = acc[1] + bias;
        res.z = acc[2] + bias; res.w = acc[3] + bias;
        *(float4*)(outrow + w0 + (quad << 2)) = res;

        __syncthreads();   // sbuf safe to overwrite next tile

        if (tt + 1 < TILES) {
            #pragma unroll
            for (int i = 0; i < 28; i++) S[i] = S2[i];
        }
    }
}

extern "C" void kernel_launch(void* const* d_in, const int* in_sizes, int n_in,
                              void* d_out, int out_size, void* d_ws, size_t ws_size,
                              hipStream_t stream) {
    (void)in_sizes; (void)n_in; (void)out_size;
    const float* x  = (const float*)d_in[0];
    const float* ow = (const float*)d_in[1];
    const float* ob = (const float*)d_in[2];
    const float* dw = (const float*)d_in[3];
    const float* db = (const float*)d_in[4];
    float* outp = (float*)d_out;

    const size_t xbytes  = (size_t)B_ * C_ * H_ * W_ * sizeof(float);
    const size_t dwbytes = (size_t)CK * COUT_ * sizeof(unsigned short);
    const size_t owbytes = (size_t)NW81 * sizeof(unsigned int);
    const dim3 grid(B_ * H_ * 2), blk(256);      // 2048 blocks, 4 tiles each
    const int dwblocks = (CK * COUT_) / 256;     // 144
    const int owblocks = (NW81 + 255) / 256;     // 21

    if (ws_size >= xbytes + dwbytes + owbytes) {
        float* xt = (float*)d_ws;
        unsigned short* dwb = (unsigned short*)((char*)d_ws + xbytes);
        unsigned int* owp = (unsigned int*)((char*)d_ws + xbytes + dwbytes);
        nchw_to_nhwc<<<dim3(B_ * H_ * 2), blk, 0, stream>>>(x, xt);
        prep_weights<<<dim3(dwblocks + owblocks), blk, 0, stream>>>(dw, dwb, ow, owp);
        dcn_fused<true, true, true><<<grid, blk, 0, stream>>>(xt, ow, owp, ob, dw, dwb, db, outp);
    } else if (ws_size >= xbytes + dwbytes) {
        float* xt = (float*)d_ws;
        unsigned short* dwb = (unsigned short*)((char*)d_ws + xbytes);
        nchw_to_nhwc<<<dim3(B_ * H_ * 2), blk, 0, stream>>>(x, xt);
        prep_weights<<<dim3(dwblocks), blk, 0, stream>>>(dw, dwb, nullptr, nullptr);
        dcn_fused<true, true, false><<<grid, blk, 0, stream>>>(xt, ow, nullptr, ob, dw, dwb, db, outp);
    } else if (ws_size >= xbytes) {
        float* xt = (float*)d_ws;
        nchw_to_nhwc<<<dim3(B_ * H_ * 2), blk, 0, stream>>>(x, xt);
        dcn_fused<true, false, false><<<grid, blk, 0, stream>>>(xt, ow, nullptr, ob, dw, nullptr, db, outp);
    } else {
        dcn_fused<false, false, false><<<grid, blk, 0, stream>>>(x, ow, nullptr, ob, dw, nullptr, db, outp);
    }
}

// Round 4
// 261.186 us; speedup vs baseline: 1.2000x; 1.2000x over previous
//
#include <hip/hip_runtime.h>

#define B_    8
#define C_    64
#define H_    128
#define W_    128
#define K_    9
#define J_    18     // 2*K
#define COUT_ 64
#define TPX   16     // pixels per tile
#define TILES 4      // tiles per block (half a row)
#define CK    576    // C_*K_
#define SROW  584    // sbuf row stride (bf16 elems)
#define NW81  (C_ * 81)                 // 5184 packed weight words
#define L2E   1.4426950408889634f       // log2(e), folded into conv weights+bias

typedef __attribute__((ext_vector_type(8))) short short8;
typedef __attribute__((ext_vector_type(4))) float float4v;
typedef __attribute__((ext_vector_type(2))) float f32x2;

// round-to-nearest-even fp32 -> bf16
__device__ __forceinline__ unsigned short f2bf(float f) {
    unsigned int u = __float_as_uint(f);
    u = u + 0x7fffu + ((u >> 16) & 1u);
    return (unsigned short)(u >> 16);
}

// conv tap (r*3+s) -> strip index r*7+s. constexpr everywhere (earlier:
// runtime-indexed S[] -> scratch demotion -> GB-scale spill).
constexpr int TMAP[9] = {0, 1, 2, 7, 8, 9, 14, 15, 16};

// -------- pre-kernel: NCHW->NHWC transpose + weight prep, one launch -----
// Blocks [0, 2048): transpose x into xt.
// Blocks [2048, 2192): dwb[i] = bf16(dw[i]).
// Blocks [2192, 2213): owp pair-pack (bf16(L2E*w_dy), bf16(L2E*w_dx)).
#define TRBLK (B_ * H_ * 2)            // 2048
#define DWBLK ((CK * COUT_) / 256)     // 144
__global__ __launch_bounds__(256)
void pre_all(const float* __restrict__ x, float* __restrict__ xt,
             const float* __restrict__ dw, unsigned short* __restrict__ dwb,
             const float* __restrict__ ow, unsigned int* __restrict__ owp) {
    __shared__ float tile[64][65];
    const int bid = blockIdx.x;
    if (bid < TRBLK) {
        const int wt  = bid & 1;
        const int h   = (bid >> 1) & 127;
        const int b   = bid >> 8;
        const int w0  = wt << 6;
        const int q   = threadIdx.x >> 6;
        const int l   = threadIdx.x & 63;
        #pragma unroll
        for (int r = 0; r < 16; r++) {
            const int c = q * 16 + r;
            tile[c][l] = x[((size_t)(b * C_ + c) * H_ + h) * W_ + w0 + l];
        }
        __syncthreads();
        #pragma unroll
        for (int r = 0; r < 16; r++) {
            const int w = q * 16 + r;
            xt[((size_t)(b * H_ + h) * W_ + w0 + w) * C_ + l] = tile[l][w];
        }
    } else if (bid < TRBLK + DWBLK) {
        const int i = (bid - TRBLK) * 256 + threadIdx.x;
        dwb[i] = f2bf(dw[i]);
    } else {
        const int i = (bid - TRBLK - DWBLK) * 256 + threadIdx.x;
        if (i < NW81) {
            const int c = i / 81, r = i - c * 81;
            const int k = r / 9,  t = r - k * 9;
            const float* s = ow + c * 162 + k * 18 + t;   // (2k)*9 = k*18
            owp[i] = (unsigned int)f2bf(s[0] * L2E) |
                     ((unsigned int)f2bf(s[9] * L2E) << 16);
        }
    }
}

// standalone fallbacks (small-workspace paths)
__global__ __launch_bounds__(256)
void nchw_to_nhwc(const float* __restrict__ x, float* __restrict__ xt) {
    __shared__ float tile[64][65];
    const int bid = blockIdx.x;
    const int wt  = bid & 1;
    const int h   = (bid >> 1) & 127;
    const int b   = bid >> 8;
    const int w0  = wt << 6;
    const int q   = threadIdx.x >> 6;
    const int l   = threadIdx.x & 63;
    #pragma unroll
    for (int r = 0; r < 16; r++) {
        const int c = q * 16 + r;
        tile[c][l] = x[((size_t)(b * C_ + c) * H_ + h) * W_ + w0 + l];
    }
    __syncthreads();
    #pragma unroll
    for (int r = 0; r < 16; r++) {
        const int w = q * 16 + r;
        xt[((size_t)(b * H_ + h) * W_ + w0 + w) * C_ + l] = tile[l][w];
    }
}
__global__ __launch_bounds__(256)
void prep_dwb(const float* __restrict__ dw, unsigned short* __restrict__ dwb) {
    const int i = blockIdx.x * 256 + threadIdx.x;
    if (i < CK * COUT_) dwb[i] = f2bf(dw[i]);
}

// ---- conv inner loop: full unroll via template recursion. Word T = k*9+t
// holds the bf16 (dy,dx) weight pair of output-pair k, tap t. One
// v_pk_fma_f32 per pixel per word.
template<int T>
__device__ __forceinline__ void conv_steps(const unsigned int* __restrict__ owc,
                                           const float (&S)[28], f32x2 (&v2)[4][9]) {
    if constexpr (T < 81) {
        const unsigned int pw = owc[T];
        const f32x2 w2 = {__uint_as_float(pw << 16),
                          __uint_as_float(pw & 0xffff0000u)};
        constexpr int k = T / 9;
        constexpr int p = TMAP[T % 9];
        #pragma unroll
        for (int px = 0; px < 4; px++) {
            const float s = S[p + px];
            v2[px][k] = __builtin_elementwise_fma(w2, (f32x2){s, s}, v2[px][k]);
        }
        conv_steps<T + 1>(owc, S, v2);
    }
}

// ---- per-pixel bilinear taps ----
// (round-1 lesson): dy/dx are bilinear SAMPLE COORDINATES — cross term
// dy*dx + constant term, so 1/sum does NOT commute through the einsum.
// Normalize here via v_rcp_f32 (invisible under bf16).
template<int I>
__device__ __forceinline__ void taps_px(const f32x2 (&w)[9], const float inv,
                                        const float (&S)[28],
                                        unsigned short* __restrict__ sb) {
    #pragma unroll
    for (int k = 0; k < 9; k++) {
        const float dy = w[k].x * inv;
        const float dx = w[k].y * inv;
        const int base = TMAP[k] + I;              // constexpr-folded
        const float a  = S[base],     bb = S[base + 1];
        const float c  = S[base + 7], dd = S[base + 8];
        const float top = fmaf(dx, bb - a, a);
        const float bot = fmaf(dx, dd - c, c);
        sb[k] = f2bf(fmaf(dy, bot - top, top));
    }
}

// ---- 4x7 input strip load (rows h-1..h+2, cols wbase-1..wbase+5) ----
template<bool NHWC>
__device__ __forceinline__ void load_strip(const float* __restrict__ xsrc,
                                           int b, int h, int wbase, int lane,
                                           float (&S)[28]) {
    if (h >= 1 && h <= H_ - 3 && wbase >= 1 && wbase <= W_ - 6) {
        // interior fast path: bounds are wave-uniform -> scalar branch
        const float* p0 = NHWC
            ? xsrc + ((size_t)(b * H_ + (h - 1)) * W_ + (wbase - 1)) * C_ + lane
            : xsrc + ((size_t)(b * C_ + lane) * H_ + (h - 1)) * W_ + (wbase - 1);
        const int rs = NHWC ? (W_ * C_) : W_;
        const int cs = NHWC ? C_ : 1;
        #pragma unroll
        for (int r = 0; r < 4; r++)
            #pragma unroll
            for (int s = 0; s < 7; s++)
                S[r * 7 + s] = p0[r * rs + s * cs];
    } else {
        #pragma unroll
        for (int r = 0; r < 4; r++) {
            const int y = h - 1 + r;
            const bool yv = (unsigned)y < (unsigned)H_;
            #pragma unroll
            for (int s = 0; s < 7; s++) {
                const int xx = wbase - 1 + s;
                const bool ok = yv && ((unsigned)xx < (unsigned)W_);
                const float* p = NHWC
                    ? xsrc + ((size_t)(b * H_ + (y & 127)) * W_ + (xx & 127)) * C_ + lane
                    : xsrc + ((size_t)(b * C_ + lane) * H_ + (y & 127)) * W_ + (xx & 127);
                S[r * 7 + s] = ok ? *p : 0.0f;
            }
        }
    }
}

// hoisted per-block context (all values tile-invariant)
struct TileCtx {
    const float* xsrc;
    const unsigned int* owc;       // lane's 81 packed weights (LDS)
    const float2* obp;             // lane's bias pairs
    const unsigned short* arow;    // phase-B A-fragment base (LDS)
    const unsigned short* bbase;   // PREB: bf16 deform-w row
    const float* brow0;            // !PREB: f32 deform-w row
    unsigned short* sb;            // taps output base (LDS)
    float* outrow;                 // out + ((b*COUT+o)*H + h)*W
    float bias;
    int b, h, w0base, wave, lane, quad;
};

// ---- one 16-px tile: conv -> (prefetch next strip) -> softmax -> taps ->
// MFMA. Template recursion keeps EVERYTHING straight-line: round-3's
// runtime tile loop (conditional S2 + array copy) demoted the strips to
// scratch (FETCH 19.5->428 MB). No loop-carried arrays here: the next
// strip is a fresh SSA array passed into the next instantiation.
template<int TT, bool NHWC, bool PREB>
__device__ __forceinline__ void tile_body(const TileCtx& cx, const float (&S)[28]) {
    // ---- phase A: conv + softmax + bilinear, 4 px per wave ----
    f32x2 v2[4][9];
    #pragma unroll
    for (int p = 0; p < 9; p++) {
        const float2 f = cx.obp[p];              // bias, L1-hot (4.6 KB)
        const f32x2 b2 = {f.x * L2E, f.y * L2E};
        v2[0][p] = b2; v2[1][p] = b2; v2[2][p] = b2; v2[3][p] = b2;
    }
    conv_steps<0>(cx.owc, S, v2);

    // prefetch next tile's strip: ~1100-cycle window (exp+reduce+taps)
    // before the barrier drain claims the loads. Straight-line, no copy.
    float Sn[28];
    if constexpr (TT + 1 < TILES)
        load_strip<NHWC>(cx.xsrc, cx.b, cx.h,
                         cx.w0base + ((TT + 1) << 4) + (cx.wave << 2), cx.lane, Sn);

    // exp2 + per-px local sums. No max-subtraction: logits bounded
    // (|w|~0.05 scale), exp2 args ~ +-15, fp32-safe.
    float psum[4];
    #pragma unroll
    for (int px = 0; px < 4; px++) {
        float s = 0.0f;
        #pragma unroll
        for (int k = 0; k < 9; k++) {
            f32x2 e;
            e.x = __builtin_amdgcn_exp2f(v2[px][k].x);
            e.y = __builtin_amdgcn_exp2f(v2[px][k].y);
            v2[px][k] = e;
            s += e.x + e.y;
        }
        psum[px] = s;
    }

    // cross-lane softmax denominators (64 lanes x 18 = channel axis),
    // 4 px interleaved; xor<32 via single-inst ds_swizzle, xor32 via shfl.
    #pragma unroll
    for (int px = 0; px < 4; px++) psum[px] += __shfl_xor(psum[px], 32, 64);
#define RED_LEVEL(PAT) do { \
        const float r0_ = __uint_as_float((unsigned)__builtin_amdgcn_ds_swizzle((int)__float_as_uint(psum[0]), (PAT))); \
        const float r1_ = __uint_as_float((unsigned)__builtin_amdgcn_ds_swizzle((int)__float_as_uint(psum[1]), (PAT))); \
        const float r2_ = __uint_as_float((unsigned)__builtin_amdgcn_ds_swizzle((int)__float_as_uint(psum[2]), (PAT))); \
        const float r3_ = __uint_as_float((unsigned)__builtin_amdgcn_ds_swizzle((int)__float_as_uint(psum[3]), (PAT))); \
        psum[0] += r0_; psum[1] += r1_; psum[2] += r2_; psum[3] += r3_; \
    } while (0)
    RED_LEVEL(0x401F);   // xor 16
    RED_LEVEL(0x201F);   // xor 8
    RED_LEVEL(0x101F);   // xor 4
    RED_LEVEL(0x081F);   // xor 2
    RED_LEVEL(0x041F);   // xor 1
#undef RED_LEVEL

    const float inv0 = __builtin_amdgcn_rcpf(psum[0]);
    const float inv1 = __builtin_amdgcn_rcpf(psum[1]);
    const float inv2 = __builtin_amdgcn_rcpf(psum[2]);
    const float inv3 = __builtin_amdgcn_rcpf(psum[3]);

    taps_px<0>(v2[0], inv0, S, cx.sb);
    taps_px<1>(v2[1], inv1, S, cx.sb + SROW);
    taps_px<2>(v2[2], inv2, S, cx.sb + 2 * SROW);
    taps_px<3>(v2[3], inv3, S, cx.sb + 3 * SROW);

    __syncthreads();

    // ---- phase B: MFMA einsum. Per wave: 16 px x 16 outs, K=576 ----
    float4v acc = {0.f, 0.f, 0.f, 0.f};
    #pragma unroll
    for (int t = 0; t < 18; t++) {
        short8 afrag = *(const short8*)(cx.arow + t * 32);
        short8 bfrag;
        if (PREB) {
            bfrag = *(const short8*)(cx.bbase + t * 32);
        } else {
            const float* brow = cx.brow0 + t * 32;
            float4 b0 = *(const float4*)brow;
            float4 b1 = *(const float4*)(brow + 4);
            union { short8 s8; unsigned short u[8]; } bfu;
            bfu.u[0] = f2bf(b0.x); bfu.u[1] = f2bf(b0.y); bfu.u[2] = f2bf(b0.z); bfu.u[3] = f2bf(b0.w);
            bfu.u[4] = f2bf(b1.x); bfu.u[5] = f2bf(b1.y); bfu.u[6] = f2bf(b1.z); bfu.u[7] = f2bf(b1.w);
            bfrag = bfu.s8;
        }
        acc = __builtin_amdgcn_mfma_f32_16x16x32_bf16(afrag, bfrag, acc, 0, 0, 0);
    }
    float4 res;
    res.x = acc[0] + cx.bias; res.y = acc[1] + cx.bias;
    res.z = acc[2] + cx.bias; res.w = acc[3] + cx.bias;
    *(float4*)(cx.outrow + cx.w0base + (TT << 4) + (cx.quad << 2)) = res;

    if constexpr (TT + 1 < TILES) {
        __syncthreads();               // sbuf safe to overwrite
        tile_body<TT + 1, NHWC, PREB>(cx, Sn);
    }
}

// -------- fused kernel --------
// Round-2 lesson: latency-bound (VALUBusy 51%, Mfma 3%, HBM 5%). Fix:
// 4 tiles/block (stage ow_s + hoist phase-B constants once), prefetch
// next strip under exp/reduce/taps, XCD-chunked block mapping.
template<bool NHWC, bool PREB, bool PREP>
__global__ __launch_bounds__(256, 3)
void dcn_fused(const float* __restrict__ xsrc,
               const float* __restrict__ ow,
               const unsigned int* __restrict__ owp,
               const float* __restrict__ ob,
               const float* __restrict__ dw,
               const unsigned short* __restrict__ dwb,
               const float* __restrict__ db,
               float* __restrict__ out) {
    __shared__ __align__(16) unsigned int ow_s[NW81];             // 20736 B
    __shared__ __align__(16) unsigned short sbuf[TPX * SROW];     // 18688 B

    const int tid  = threadIdx.x;
    const int wave = tid >> 6;
    const int lane = tid & 63;

    // XCD-chunked bijective swizzle (2048 blocks, 8 XCDs, 256 each):
    // XCD x gets all half-rows of image x -> xt slice + dwb live in its L2.
    const int bid     = blockIdx.x;
    const int logical = (bid & 7) * 256 + (bid >> 3);
    const int b       = logical >> 8;
    const int h       = (logical >> 1) & 127;
    const int w0base  = (logical & 1) << 6;       // 0 or 64

    // stage packed offset weights (once per 4 tiles)
    if (PREP) {
        #pragma unroll
        for (int i = 0; i < 21; i++) {               // 5184 = 20*256 + 64
            const int idx = tid + i * 256;
            if (idx < NW81) ow_s[idx] = owp[idx];    // coalesced u32 copy
        }
    } else {
        for (int i = tid; i < NW81; i += 256) {      // fallback: pack in-kernel
            const int c = i / 81, r = i - c * 81;
            const int k = r / 9,  t = r - k * 9;
            const float* s = ow + c * 162 + k * 18 + t;
            ow_s[i] = (unsigned int)f2bf(s[0] * L2E) |
                      ((unsigned int)f2bf(s[9] * L2E) << 16);
        }
    }

    // hoisted tile-invariant context
    const int quad = lane >> 4;
    const int o    = (wave << 4) + (lane & 15);
    TileCtx cx;
    cx.xsrc   = xsrc;
    cx.owc    = ow_s + lane * 81;
    cx.obp    = (const float2*)(ob + lane * J_);
    cx.arow   = sbuf + (lane & 15) * SROW + quad * 8;
    cx.bbase  = PREB ? (dwb + (size_t)o * CK + quad * 8) : nullptr;
    cx.brow0  = PREB ? nullptr : (dw + (size_t)o * CK + quad * 8);
    cx.sb     = sbuf + (wave << 2) * SROW + lane * K_;
    cx.outrow = out + ((size_t)(b * COUT_ + o) * H_ + h) * W_;
    cx.bias   = db[o];
    cx.b = b; cx.h = h; cx.w0base = w0base;
    cx.wave = wave; cx.lane = lane; cx.quad = quad;

    // first strip: issue before the staging barrier (independent of LDS)
    float S0[28];
    load_strip<NHWC>(xsrc, b, h, w0base + (wave << 2), lane, S0);

    __syncthreads();

    tile_body<0, NHWC, PREB>(cx, S0);
}

extern "C" void kernel_launch(void* const* d_in, const int* in_sizes, int n_in,
                              void* d_out, int out_size, void* d_ws, size_t ws_size,
                              hipStream_t stream) {
    (void)in_sizes; (void)n_in; (void)out_size;
    const float* x  = (const float*)d_in[0];
    const float* ow = (const float*)d_in[1];
    const float* ob = (const float*)d_in[2];
    const float* dw = (const float*)d_in[3];
    const float* db = (const float*)d_in[4];
    float* outp = (float*)d_out;

    const size_t xbytes  = (size_t)B_ * C_ * H_ * W_ * sizeof(float);
    const size_t dwbytes = (size_t)CK * COUT_ * sizeof(unsigned short);
    const size_t owbytes = (size_t)NW81 * sizeof(unsigned int);
    const dim3 grid(B_ * H_ * 2), blk(256);      // 2048 blocks, 4 tiles each
    const int owblocks = (NW81 + 255) / 256;     // 21

    if (ws_size >= xbytes + dwbytes + owbytes) {
        float* xt = (float*)d_ws;
        unsigned short* dwb = (unsigned short*)((char*)d_ws + xbytes);
        unsigned int* owp = (unsigned int*)((char*)d_ws + xbytes + dwbytes);
        pre_all<<<dim3(TRBLK + DWBLK + owblocks), blk, 0, stream>>>(x, xt, dw, dwb, ow, owp);
        dcn_fused<true, true, true><<<grid, blk, 0, stream>>>(xt, ow, owp, ob, dw, dwb, db, outp);
    } else if (ws_size >= xbytes + dwbytes) {
        float* xt = (float*)d_ws;
        unsigned short* dwb = (unsigned short*)((char*)d_ws + xbytes);
        nchw_to_nhwc<<<dim3(B_ * H_ * 2), blk, 0, stream>>>(x, xt);
        prep_dwb<<<dim3((CK * COUT_ + 255) / 256), blk, 0, stream>>>(dw, dwb);
        dcn_fused<true, true, false><<<grid, blk, 0, stream>>>(xt, ow, nullptr, ob, dw, dwb, db, outp);
    } else if (ws_size >= xbytes) {
        float* xt = (float*)d_ws;
        nchw_to_nhwc<<<dim3(B_ * H_ * 2), blk, 0, stream>>>(x, xt);
        dcn_fused<true, false, false><<<grid, blk, 0, stream>>>(xt, ow, nullptr, ob, dw, nullptr, db, outp);
    } else {
        dcn_fused<false, false, false><<<grid, blk, 0, stream>>>(x, ow, nullptr, ob, dw, nullptr, db, outp);
    }
}

// Round 5
// 196.668 us; speedup vs baseline: 1.5936x; 1.3281x over previous
//
#include <hip/hip_runtime.h>

#define B_    8
#define C_    64
#define H_    128
#define W_    128
#define K_    9
#define J_    18     // 2*K
#define COUT_ 64
#define TPX   16     // pixels per tile
#define CK    576    // C_*K_
#define SROW  584    // sbuf row stride (bf16 elems)
#define NW81  (C_ * 81)                 // 5184 packed weight words
#define L2E   1.4426950408889634f       // log2(e), folded into conv weights+bias

typedef __attribute__((ext_vector_type(8))) short short8;
typedef __attribute__((ext_vector_type(4))) float float4v;
typedef __attribute__((ext_vector_type(2))) float f32x2;

// round-to-nearest-even fp32 -> bf16
__device__ __forceinline__ unsigned short f2bf(float f) {
    unsigned int u = __float_as_uint(f);
    u = u + 0x7fffu + ((u >> 16) & 1u);
    return (unsigned short)(u >> 16);
}

// conv tap (r*3+s) -> strip index r*7+s. constexpr everywhere (earlier:
// runtime-indexed S[] -> scratch demotion -> GB-scale spill).
constexpr int TMAP[9] = {0, 1, 2, 7, 8, 9, 14, 15, 16};

// -------- pre-kernel: NCHW->NHWC transpose + weight prep, one launch -----
#define TRBLK (B_ * H_ * 2)            // 2048
#define DWBLK ((CK * COUT_) / 256)     // 144
__global__ __launch_bounds__(256)
void pre_all(const float* __restrict__ x, float* __restrict__ xt,
             const float* __restrict__ dw, unsigned short* __restrict__ dwb,
             const float* __restrict__ ow, unsigned int* __restrict__ owp) {
    __shared__ float tile[64][65];
    const int bid = blockIdx.x;
    if (bid < TRBLK) {
        const int wt  = bid & 1;
        const int h   = (bid >> 1) & 127;
        const int b   = bid >> 8;
        const int w0  = wt << 6;
        const int q   = threadIdx.x >> 6;
        const int l   = threadIdx.x & 63;
        #pragma unroll
        for (int r = 0; r < 16; r++) {
            const int c = q * 16 + r;
            tile[c][l] = x[((size_t)(b * C_ + c) * H_ + h) * W_ + w0 + l];
        }
        __syncthreads();
        #pragma unroll
        for (int r = 0; r < 16; r++) {
            const int w = q * 16 + r;
            xt[((size_t)(b * H_ + h) * W_ + w0 + w) * C_ + l] = tile[l][w];
        }
    } else if (bid < TRBLK + DWBLK) {
        const int i = (bid - TRBLK) * 256 + threadIdx.x;
        dwb[i] = f2bf(dw[i]);
    } else {
        const int i = (bid - TRBLK - DWBLK) * 256 + threadIdx.x;
        if (i < NW81) {
            const int c = i / 81, r = i - c * 81;
            const int k = r / 9,  t = r - k * 9;
            const float* s = ow + c * 162 + k * 18 + t;   // (2k)*9 = k*18
            owp[i] = (unsigned int)f2bf(s[0] * L2E) |
                     ((unsigned int)f2bf(s[9] * L2E) << 16);
        }
    }
}

// standalone fallbacks (small-workspace paths)
__global__ __launch_bounds__(256)
void nchw_to_nhwc(const float* __restrict__ x, float* __restrict__ xt) {
    __shared__ float tile[64][65];
    const int bid = blockIdx.x;
    const int wt  = bid & 1;
    const int h   = (bid >> 1) & 127;
    const int b   = bid >> 8;
    const int w0  = wt << 6;
    const int q   = threadIdx.x >> 6;
    const int l   = threadIdx.x & 63;
    #pragma unroll
    for (int r = 0; r < 16; r++) {
        const int c = q * 16 + r;
        tile[c][l] = x[((size_t)(b * C_ + c) * H_ + h) * W_ + w0 + l];
    }
    __syncthreads();
    #pragma unroll
    for (int r = 0; r < 16; r++) {
        const int w = q * 16 + r;
        xt[((size_t)(b * H_ + h) * W_ + w0 + w) * C_ + l] = tile[l][w];
    }
}
__global__ __launch_bounds__(256)
void prep_dwb(const float* __restrict__ dw, unsigned short* __restrict__ dwb) {
    const int i = blockIdx.x * 256 + threadIdx.x;
    if (i < CK * COUT_) dwb[i] = f2bf(dw[i]);
}

// ---- conv inner loop: full unroll via template recursion. Word T = k*9+t
// holds the bf16 (dy,dx) weight pair of output-pair k, tap t. One
// v_pk_fma_f32 per pixel per word.
template<int T>
__device__ __forceinline__ void conv_steps(const unsigned int* __restrict__ owc,
                                           const float (&S)[28], f32x2 (&v2)[4][9]) {
    if constexpr (T < 81) {
        const unsigned int pw = owc[T];
        const f32x2 w2 = {__uint_as_float(pw << 16),
                          __uint_as_float(pw & 0xffff0000u)};
        constexpr int k = T / 9;
        constexpr int p = TMAP[T % 9];
        #pragma unroll
        for (int px = 0; px < 4; px++) {
            const float s = S[p + px];
            v2[px][k] = __builtin_elementwise_fma(w2, (f32x2){s, s}, v2[px][k]);
        }
        conv_steps<T + 1>(owc, S, v2);
    }
}

// ---- per-pixel bilinear taps ----
// (round-1 lesson): dy/dx are bilinear SAMPLE COORDINATES — cross term
// dy*dx + constant term, so 1/sum does NOT commute through the einsum.
// Normalize here via v_rcp_f32 (invisible under bf16).
template<int I>
__device__ __forceinline__ void taps_px(const f32x2 (&w)[9], const float inv,
                                        const float (&S)[28],
                                        unsigned short* __restrict__ sb) {
    #pragma unroll
    for (int k = 0; k < 9; k++) {
        const float dy = w[k].x * inv;
        const float dx = w[k].y * inv;
        const int base = TMAP[k] + I;              // constexpr-folded
        const float a  = S[base],     bb = S[base + 1];
        const float c  = S[base + 7], dd = S[base + 8];
        const float top = fmaf(dx, bb - a, a);
        const float bot = fmaf(dx, dd - c, c);
        sb[k] = f2bf(fmaf(dy, bot - top, top));
    }
}

// ---- 4x7 input strip load (rows h-1..h+2, cols wbase-1..wbase+5) ----
template<bool NHWC>
__device__ __forceinline__ void load_strip(const float* __restrict__ xsrc,
                                           int b, int h, int wbase, int lane,
                                           float (&S)[28]) {
    if (h >= 1 && h <= H_ - 3 && wbase >= 1 && wbase <= W_ - 6) {
        // interior fast path: bounds are wave-uniform -> scalar branch
        const float* p0 = NHWC
            ? xsrc + ((size_t)(b * H_ + (h - 1)) * W_ + (wbase - 1)) * C_ + lane
            : xsrc + ((size_t)(b * C_ + lane) * H_ + (h - 1)) * W_ + (wbase - 1);
        const int rs = NHWC ? (W_ * C_) : W_;
        const int cs = NHWC ? C_ : 1;
        #pragma unroll
        for (int r = 0; r < 4; r++)
            #pragma unroll
            for (int s = 0; s < 7; s++)
                S[r * 7 + s] = p0[r * rs + s * cs];
    } else {
        #pragma unroll
        for (int r = 0; r < 4; r++) {
            const int y = h - 1 + r;
            const bool yv = (unsigned)y < (unsigned)H_;
            #pragma unroll
            for (int s = 0; s < 7; s++) {
                const int xx = wbase - 1 + s;
                const bool ok = yv && ((unsigned)xx < (unsigned)W_);
                const float* p = NHWC
                    ? xsrc + ((size_t)(b * H_ + (y & 127)) * W_ + (xx & 127)) * C_ + lane
                    : xsrc + ((size_t)(b * C_ + lane) * H_ + (y & 127)) * W_ + (xx & 127);
                S[r * 7 + s] = ok ? *p : 0.0f;
            }
        }
    }
}

// ---- phase A: conv + exp2 + cross-lane reduce -> inv[4]; numerators in v2
__device__ __forceinline__ void phaseA(const unsigned int* __restrict__ owc,
                                       const float2* __restrict__ obp,
                                       const float (&S)[28],
                                       f32x2 (&v2)[4][9], float (&inv)[4]) {
    #pragma unroll
    for (int p = 0; p < 9; p++) {
        const float2 f = obp[p];                 // bias, L1-hot (4.6 KB)
        const f32x2 b2 = {f.x * L2E, f.y * L2E};
        v2[0][p] = b2; v2[1][p] = b2; v2[2][p] = b2; v2[3][p] = b2;
    }
    conv_steps<0>(owc, S, v2);

    // exp2 + per-px local sums. No max-subtraction: logits bounded
    // (|w|~0.05 scale), exp2 args ~ +-15, fp32-safe.
    float psum[4];
    #pragma unroll
    for (int px = 0; px < 4; px++) {
        float s = 0.0f;
        #pragma unroll
        for (int k = 0; k < 9; k++) {
            f32x2 e;
            e.x = __builtin_amdgcn_exp2f(v2[px][k].x);
            e.y = __builtin_amdgcn_exp2f(v2[px][k].y);
            v2[px][k] = e;
            s += e.x + e.y;
        }
        psum[px] = s;
    }

    // cross-lane softmax denominators (64 lanes x 18 = channel axis),
    // 4 px interleaved; xor<32 via single-inst ds_swizzle, xor32 via shfl.
    #pragma unroll
    for (int px = 0; px < 4; px++) psum[px] += __shfl_xor(psum[px], 32, 64);
#define RED_LEVEL(PAT) do { \
        const float r0_ = __uint_as_float((unsigned)__builtin_amdgcn_ds_swizzle((int)__float_as_uint(psum[0]), (PAT))); \
        const float r1_ = __uint_as_float((unsigned)__builtin_amdgcn_ds_swizzle((int)__float_as_uint(psum[1]), (PAT))); \
        const float r2_ = __uint_as_float((unsigned)__builtin_amdgcn_ds_swizzle((int)__float_as_uint(psum[2]), (PAT))); \
        const float r3_ = __uint_as_float((unsigned)__builtin_amdgcn_ds_swizzle((int)__float_as_uint(psum[3]), (PAT))); \
        psum[0] += r0_; psum[1] += r1_; psum[2] += r2_; psum[3] += r3_; \
    } while (0)
    RED_LEVEL(0x401F);   // xor 16
    RED_LEVEL(0x201F);   // xor 8
    RED_LEVEL(0x101F);   // xor 4
    RED_LEVEL(0x081F);   // xor 2
    RED_LEVEL(0x041F);   // xor 1
#undef RED_LEVEL

    inv[0] = __builtin_amdgcn_rcpf(psum[0]);
    inv[1] = __builtin_amdgcn_rcpf(psum[1]);
    inv[2] = __builtin_amdgcn_rcpf(psum[2]);
    inv[3] = __builtin_amdgcn_rcpf(psum[3]);
}

// ---- phase B: MFMA einsum. Per wave: 16 px x 16 outs, K=576 ----
template<bool PREB>
__device__ __forceinline__ void phaseB(const unsigned short* __restrict__ arow,
                                       const unsigned short* __restrict__ bbase,
                                       const float* __restrict__ brow0,
                                       float bias, float* __restrict__ outp) {
    float4v acc = {0.f, 0.f, 0.f, 0.f};
    #pragma unroll
    for (int t = 0; t < 18; t++) {
        short8 afrag = *(const short8*)(arow + t * 32);
        short8 bfrag;
        if (PREB) {
            bfrag = *(const short8*)(bbase + t * 32);
        } else {
            const float* brow = brow0 + t * 32;
            float4 b0 = *(const float4*)brow;
            float4 b1 = *(const float4*)(brow + 4);
            union { short8 s8; unsigned short u[8]; } bfu;
            bfu.u[0] = f2bf(b0.x); bfu.u[1] = f2bf(b0.y); bfu.u[2] = f2bf(b0.z); bfu.u[3] = f2bf(b0.w);
            bfu.u[4] = f2bf(b1.x); bfu.u[5] = f2bf(b1.y); bfu.u[6] = f2bf(b1.z); bfu.u[7] = f2bf(b1.w);
            bfrag = bfu.s8;
        }
        acc = __builtin_amdgcn_mfma_f32_16x16x32_bf16(afrag, bfrag, acc, 0, 0, 0);
    }
    float4 res;
    res.x = acc[0] + bias; res.y = acc[1] + bias;
    res.z = acc[2] + bias; res.w = acc[3] + bias;
    *(float4*)outp = res;
}

// -------- fused kernel: 2 tiles (32 px) per block, FLAT straight-line -----
// Round-3/4 lesson: any tile-loop wrapper (runtime loop OR template
// recursion + ctx struct) broke SROA -> scratch spill (WRITE 222-304 MB).
// Round-2's flat body was spill-free at VGPR 72. So: write the tile body
// TWICE with distinct locals. Amortizes ow_s staging + setup x2 and
// overlaps tile-1's strip loads + conv (VALU) with tile-0's phase B (MFMA).
template<bool NHWC, bool PREB, bool PREP>
__global__ __launch_bounds__(256, 3)
void dcn_fused(const float* __restrict__ xsrc,
               const float* __restrict__ ow,
               const unsigned int* __restrict__ owp,
               const float* __restrict__ ob,
               const float* __restrict__ dw,
               const unsigned short* __restrict__ dwb,
               const float* __restrict__ db,
               float* __restrict__ out) {
    __shared__ __align__(16) unsigned int ow_s[NW81];             // 20736 B
    __shared__ __align__(16) unsigned short sbuf[TPX * SROW];     // 18688 B

    const int tid  = threadIdx.x;
    const int wave = tid >> 6;
    const int lane = tid & 63;

    // XCD-chunked bijective swizzle (4096 blocks, 8 XCDs, 512 each):
    // XCD x gets all tiles of image x -> its xt slice + dwb live in L2.
    const int bid     = blockIdx.x;
    const int logical = (bid & 7) * 512 + (bid >> 3);
    const int b       = logical >> 9;
    const int rem     = logical & 511;
    const int h       = rem >> 2;
    const int w0base  = (rem & 3) << 5;           // 0/32/64/96; tiles at +0,+16

    // stage packed offset weights (once per 2 tiles)
    if (PREP) {
        #pragma unroll
        for (int i = 0; i < 20; i++)
            ow_s[tid + i * 256] = owp[tid + i * 256];   // coalesced u32 copy
        if (tid < 64) ow_s[5120 + tid] = owp[5120 + tid];
    } else {
        for (int i = tid; i < NW81; i += 256) {      // fallback: pack in-kernel
            const int c = i / 81, r = i - c * 81;
            const int k = r / 9,  t = r - k * 9;
            const float* s = ow + c * 162 + k * 18 + t;
            ow_s[i] = (unsigned int)f2bf(s[0] * L2E) |
                      ((unsigned int)f2bf(s[9] * L2E) << 16);
        }
    }

    // hoisted tile-invariant locals (plain scalars/pointers, no struct)
    const int quad = lane >> 4;
    const int o    = (wave << 4) + (lane & 15);
    const unsigned int* owc = ow_s + lane * 81;
    const float2* obp = (const float2*)(ob + lane * J_);
    const unsigned short* arow  = sbuf + (lane & 15) * SROW + quad * 8;
    const unsigned short* bbase = PREB ? (dwb + (size_t)o * CK + quad * 8) : nullptr;
    const float* brow0 = PREB ? nullptr : (dw + (size_t)o * CK + quad * 8);
    const float bias = db[o];
    float* outrow = out + ((size_t)(b * COUT_ + o) * H_ + h) * W_ + w0base + (quad << 2);
    unsigned short* sb = sbuf + (wave << 2) * SROW + lane * K_;

    // tile-0 strip: issue before the staging barrier (overlaps staging)
    float S0[28];
    load_strip<NHWC>(xsrc, b, h, w0base + (wave << 2), lane, S0);

    __syncthreads();

    // ================= tile 0 =================
    f32x2 v2a[4][9];
    float inva[4];
    phaseA(owc, obp, S0, v2a, inva);
    taps_px<0>(v2a[0], inva[0], S0, sb);
    taps_px<1>(v2a[1], inva[1], S0, sb + SROW);
    taps_px<2>(v2a[2], inva[2], S0, sb + 2 * SROW);
    taps_px<3>(v2a[3], inva[3], S0, sb + 3 * SROW);

    __syncthreads();

    // tile-1 strip loads first (long latency, covered by phase-B0 below)
    float S1[28];
    load_strip<NHWC>(xsrc, b, h, w0base + 16 + (wave << 2), lane, S1);

    // phase B of tile 0 (MFMA pipe) ...
    phaseB<PREB>(arow, bbase, brow0, bias, outrow);

    // ... overlapped (same region, no barrier) with tile-1 conv (VALU pipe)
    f32x2 v2b[4][9];
    float invb[4];
    phaseA(owc, obp, S1, v2b, invb);

    __syncthreads();   // all waves done reading sbuf in phase-B0

    // ================= tile 1 =================
    taps_px<0>(v2b[0], invb[0], S1, sb);
    taps_px<1>(v2b[1], invb[1], S1, sb + SROW);
    taps_px<2>(v2b[2], invb[2], S1, sb + 2 * SROW);
    taps_px<3>(v2b[3], invb[3], S1, sb + 3 * SROW);

    __syncthreads();

    phaseB<PREB>(arow, bbase, brow0, bias, outrow + 16);
}

extern "C" void kernel_launch(void* const* d_in, const int* in_sizes, int n_in,
                              void* d_out, int out_size, void* d_ws, size_t ws_size,
                              hipStream_t stream) {
    (void)in_sizes; (void)n_in; (void)out_size;
    const float* x  = (const float*)d_in[0];
    const float* ow = (const float*)d_in[1];
    const float* ob = (const float*)d_in[2];
    const float* dw = (const float*)d_in[3];
    const float* db = (const float*)d_in[4];
    float* outp = (float*)d_out;

    const size_t xbytes  = (size_t)B_ * C_ * H_ * W_ * sizeof(float);
    const size_t dwbytes = (size_t)CK * COUT_ * sizeof(unsigned short);
    const size_t owbytes = (size_t)NW81 * sizeof(unsigned int);
    const dim3 grid(B_ * H_ * 4), blk(256);      // 4096 blocks, 2 tiles each
    const int owblocks = (NW81 + 255) / 256;     // 21

    if (ws_size >= xbytes + dwbytes + owbytes) {
        float* xt = (float*)d_ws;
        unsigned short* dwb = (unsigned short*)((char*)d_ws + xbytes);
        unsigned int* owp = (unsigned int*)((char*)d_ws + xbytes + dwbytes);
        pre_all<<<dim3(TRBLK + DWBLK + owblocks), blk, 0, stream>>>(x, xt, dw, dwb, ow, owp);
        dcn_fused<true, true, true><<<grid, blk, 0, stream>>>(xt, ow, owp, ob, dw, dwb, db, outp);
    } else if (ws_size >= xbytes + dwbytes) {
        float* xt = (float*)d_ws;
        unsigned short* dwb = (unsigned short*)((char*)d_ws + xbytes);
        nchw_to_nhwc<<<dim3(B_ * H_ * 2), blk, 0, stream>>>(x, xt);
        prep_dwb<<<dim3((CK * COUT_ + 255) / 256), blk, 0, stream>>>(dw, dwb);
        dcn_fused<true, true, false><<<grid, blk, 0, stream>>>(xt, ow, nullptr, ob, dw, dwb, db, outp);
    } else if (ws_size >= xbytes) {
        float* xt = (float*)d_ws;
        nchw_to_nhwc<<<dim3(B_ * H_ * 2), blk, 0, stream>>>(x, xt);
        dcn_fused<true, false, false><<<grid, blk, 0, stream>>>(xt, ow, nullptr, ob, dw, nullptr, db, outp);
    } else {
        dcn_fused<false, false, false><<<grid, blk, 0, stream>>>(x, ow, nullptr, ob, dw, nullptr, db, outp);
    }
}